// Round 5
// baseline (146.514 us; speedup 1.0000x reference)
//
#include <hip/hip_runtime.h>
#include <math.h>

#define NB 1024
#define N 256
#define ROWS 4
#define EPS 1e-6f
#define SQRT_EPS 1e-3f   // sqrt(1e-6)

__device__ __forceinline__ float fast_rcp(float x) {
    return __builtin_amdgcn_rcpf(x);      // v_rcp_f32
}

__device__ __forceinline__ float sigmoidf(float x) {
    return fast_rcp(1.0f + __expf(-x));
}

__device__ __forceinline__ float fast_tanh(float x) {
    float ax = fabsf(x);
    float e  = __expf(2.0f * ax);
    float t  = 1.0f - 2.0f * fast_rcp(e + 1.0f);   // e=inf -> t=1
    return copysignf(t, x);
}

__device__ __forceinline__ float dot4(float4 a, float4 b) {
    return a.x * b.x + a.y * b.y + a.z * b.z + a.w * b.w;
}

// Block: 256 threads = 4 waves. Wave lane layout: ns = lane>>2 (16 neuron
// slots), ks = lane&3 (4 k-lanes). A 4-lane group reads 64 consecutive bytes
// of one W row -> coalesced (16 lines / KB, optimal). k-sum finished by
// 2-step shfl_xor butterfly within the group.
__global__ __launch_bounds__(256) void mlp_kernel(
    const float* __restrict__ x,
    const float* __restrict__ Wd1, const float* __restrict__ bd1,
    const float* __restrict__ Wd2, const float* __restrict__ bd2,
    const float* __restrict__ Wu1, const float* __restrict__ bu1,
    const float* __restrict__ Wu2, const float* __restrict__ bu2,
    const float* __restrict__ Wm1, const float* __restrict__ bm1,
    const float* __restrict__ Wm2, const float* __restrict__ bm2,
    const float* __restrict__ v,
    float* __restrict__ out_mean, float* __restrict__ out_z,
    float* __restrict__ ws_a, float* __restrict__ ws_tp, float* __restrict__ ws_s)
{
    __shared__ float xs[ROWS][N];        // 4 KB
    __shared__ float h1[3][ROWS][N];     // 12 KB layer-1 activations
    __shared__ float h2[3][ROWS][N];     // 12 KB layer-2 results (d,u,m)
    __shared__ float red1[4][3 * ROWS];
    __shared__ float red2[4][ROWS];

    const int tid  = threadIdx.x;
    const int w    = tid >> 6;
    const int lane = tid & 63;
    const int ns   = lane >> 2;
    const int ks   = lane & 3;
    const int b0   = blockIdx.x * ROWS;

    // ---- load x rows (coalesced float4) ----
    ((float4*)xs)[tid] = ((const float4*)(x + (size_t)b0 * N))[tid];

    float vv[ROWS];
    #pragma unroll
    for (int r = 0; r < ROWS; ++r)
        vv[r] = v[(size_t)(b0 + r) * N + tid];

    __syncthreads();

    // ---- layer 1: coalesced W reads, butterfly k-reduce ----
    #pragma unroll
    for (int p = 0; p < 4; ++p) {
        const int n = w * 64 + p * 16 + ns;
        const float4* w1 = (const float4*)(Wd1 + (size_t)n * N);
        const float4* w2 = (const float4*)(Wu1 + (size_t)n * N);
        const float4* w3 = (const float4*)(Wm1 + (size_t)n * N);
        float acc[12];
        #pragma unroll
        for (int i = 0; i < 12; ++i) acc[i] = 0.f;
        #pragma unroll 4
        for (int kb = 0; kb < 16; ++kb) {
            const int ko = kb * 4 + ks;       // float4 index into row
            float4 a1 = w1[ko];
            float4 a2 = w2[ko];
            float4 a3 = w3[ko];
            #pragma unroll
            for (int r = 0; r < ROWS; ++r) {
                float4 xv = *(const float4*)&xs[r][ko * 4];
                acc[r]     += dot4(a1, xv);
                acc[4 + r] += dot4(a2, xv);
                acc[8 + r] += dot4(a3, xv);
            }
        }
        #pragma unroll
        for (int i = 0; i < 12; ++i) {
            acc[i] += __shfl_xor(acc[i], 1, 64);
            acc[i] += __shfl_xor(acc[i], 2, 64);
        }
        float b1 = bd1[n], b2 = bu1[n], b3 = bm1[n];
        h1[0][ks][n] = sigmoidf(acc[0 + ks] + b1);
        h1[1][ks][n] = sigmoidf(acc[4 + ks] + b2);
        h1[2][ks][n] = fast_tanh(acc[8 + ks] + b3);
    }
    __syncthreads();

    // ---- layer 2: same scheme, inputs from h1 ----
    #pragma unroll
    for (int p = 0; p < 4; ++p) {
        const int n = w * 64 + p * 16 + ns;
        const float4* w1 = (const float4*)(Wd2 + (size_t)n * N);
        const float4* w2 = (const float4*)(Wu2 + (size_t)n * N);
        const float4* w3 = (const float4*)(Wm2 + (size_t)n * N);
        float acc[12];
        #pragma unroll
        for (int i = 0; i < 12; ++i) acc[i] = 0.f;
        #pragma unroll 4
        for (int kb = 0; kb < 16; ++kb) {
            const int ko = kb * 4 + ks;
            float4 a1 = w1[ko];
            float4 a2 = w2[ko];
            float4 a3 = w3[ko];
            #pragma unroll
            for (int r = 0; r < ROWS; ++r) {
                float4 hd = *(const float4*)&h1[0][r][ko * 4];
                float4 hu = *(const float4*)&h1[1][r][ko * 4];
                float4 hm = *(const float4*)&h1[2][r][ko * 4];
                acc[r]     += dot4(a1, hd);
                acc[4 + r] += dot4(a2, hu);
                acc[8 + r] += dot4(a3, hm);
            }
        }
        #pragma unroll
        for (int i = 0; i < 12; ++i) {
            acc[i] += __shfl_xor(acc[i], 1, 64);
            acc[i] += __shfl_xor(acc[i], 2, 64);
        }
        float b1 = bd2[n], b2 = bu2[n], b3 = bm2[n];
        h2[0][ks][n] = sigmoidf(acc[0 + ks] + b1);   // d
        h2[1][ks][n] = sigmoidf(acc[4 + ks] + b2);   // u
        h2[2][ks][n] = fast_tanh(acc[8 + ks] + b3);  // m
    }
    __syncthreads();

    // ---- epilogue (as R3): thread t = column, 2 reduction rounds ----
    const int wid = tid >> 6;

    float d_[ROWS], u_[ROWS], m_[ROWS], inv_d[ROWS];
    float vals[3 * ROWS];
    #pragma unroll
    for (int r = 0; r < ROWS; ++r) {
        d_[r] = h2[0][r][tid];
        u_[r] = h2[1][r][tid];
        m_[r] = h2[2][r][tid];
        inv_d[r] = fast_rcp(d_[r]);
        vals[3 * r + 0] = u_[r];
        vals[3 * r + 1] = u_[r] * u_[r] * inv_d[r];
        vals[3 * r + 2] = vv[r];
    }
    #pragma unroll
    for (int k = 0; k < 3 * ROWS; ++k) {
        #pragma unroll
        for (int off = 32; off > 0; off >>= 1)
            vals[k] += __shfl_down(vals[k], off, 64);
    }
    if (lane == 0) {
        #pragma unroll
        for (int k = 0; k < 3 * ROWS; ++k) red1[wid][k] = vals[k];
    }
    __syncthreads();

    float a_[ROWS], s_[ROWS], tp_[ROWS], Sv_[ROWS];
    float vals2[ROWS];
    #pragma unroll
    for (int r = 0; r < ROWS; ++r) {
        float Su = red1[0][3*r+0] + red1[1][3*r+0] + red1[2][3*r+0] + red1[3][3*r+0];
        float q  = red1[0][3*r+1] + red1[1][3*r+1] + red1[2][3*r+1] + red1[3][3*r+1];
        Sv_[r]   = red1[0][3*r+2] + red1[1][3*r+2] + red1[2][3*r+2] + red1[3][3*r+2];
        float utDu  = q + EPS * Su * Su;
        float sqeta = rsqrtf(1.0f + utDu);
        float right = (1.0f - sqeta) / utDu;
        float a  = sqrtf(inv_d[r] + EPS);
        float s  = u_[r] * a + SQRT_EPS * (Su - u_[r]);
        float tp = right * (u_[r] * inv_d[r] + EPS * Su);
        a_[r] = a; s_[r] = s; tp_[r] = tp;
        vals2[r] = s * vv[r];
    }
    #pragma unroll
    for (int r = 0; r < ROWS; ++r) {
        #pragma unroll
        for (int off = 32; off > 0; off >>= 1)
            vals2[r] += __shfl_down(vals2[r], off, 64);
    }
    if (lane == 0) {
        #pragma unroll
        for (int r = 0; r < ROWS; ++r) red2[wid][r] = vals2[r];
    }
    __syncthreads();

    #pragma unroll
    for (int r = 0; r < ROWS; ++r) {
        const size_t row = (size_t)(b0 + r) * N + tid;
        float sv = red2[0][r] + red2[1][r] + red2[2][r] + red2[3][r];
        float z  = SQRT_EPS * Sv_[r] + (a_[r] - SQRT_EPS) * vv[r] - tp_[r] * sv + m_[r];
        out_mean[row] = m_[r];
        out_z[row]    = z;
        ws_a[row]     = a_[r];
        ws_tp[row]    = tp_[r];
        ws_s[row]     = s_[r];
    }
}

// R[b,i,j] = SQRT_EPS + (i==j)*(a_i - SQRT_EPS) - tp_i * s_j
__global__ __launch_bounds__(256) void r_kernel(
    const float* __restrict__ ws_a, const float* __restrict__ ws_tp,
    const float* __restrict__ ws_s, float* __restrict__ R)
{
    __shared__ float s_lds[N];
    __shared__ float a_lds[64];
    __shared__ float tp_lds[64];

    const int tid   = threadIdx.x;
    const int b     = blockIdx.x >> 2;
    const int chunk = blockIdx.x & 3;
    const int ibase = chunk * 64;

    s_lds[tid] = ws_s[(size_t)b * N + tid];
    if (tid < 64) {
        a_lds[tid]  = ws_a[(size_t)b * N + ibase + tid];
        tp_lds[tid] = ws_tp[(size_t)b * N + ibase + tid];
    }
    __syncthreads();

    const int j4 = tid & 63;      // which float4 along j
    const int il = tid >> 6;      // row within group of 4
    const float4 sv = ((const float4*)s_lds)[j4];
    float4* Rb = (float4*)(R + (size_t)b * N * N);
    const int jb = j4 * 4;

    #pragma unroll
    for (int it = 0; it < 16; ++it) {
        const int i_loc = it * 4 + il;
        const int i     = ibase + i_loc;
        const float a   = a_lds[i_loc];
        const float tp  = tp_lds[i_loc];
        float4 o;
        o.x = SQRT_EPS - tp * sv.x;
        o.y = SQRT_EPS - tp * sv.y;
        o.z = SQRT_EPS - tp * sv.z;
        o.w = SQRT_EPS - tp * sv.w;
        if (i >= jb && i < jb + 4) {
            const float add = a - SQRT_EPS;
            if      (i == jb)     o.x += add;
            else if (i == jb + 1) o.y += add;
            else if (i == jb + 2) o.z += add;
            else                  o.w += add;
        }
        Rb[(size_t)i * 64 + j4] = o;
    }
}

extern "C" void kernel_launch(void* const* d_in, const int* in_sizes, int n_in,
                              void* d_out, int out_size, void* d_ws, size_t ws_size,
                              hipStream_t stream) {
    const float* x   = (const float*)d_in[0];
    const float* Wd1 = (const float*)d_in[1];
    const float* bd1 = (const float*)d_in[2];
    const float* Wd2 = (const float*)d_in[3];
    const float* bd2 = (const float*)d_in[4];
    const float* Wu1 = (const float*)d_in[5];
    const float* bu1 = (const float*)d_in[6];
    const float* Wu2 = (const float*)d_in[7];
    const float* bu2 = (const float*)d_in[8];
    const float* Wm1 = (const float*)d_in[9];
    const float* bm1 = (const float*)d_in[10];
    const float* Wm2 = (const float*)d_in[11];
    const float* bm2 = (const float*)d_in[12];
    const float* v   = (const float*)d_in[13];

    float* out      = (float*)d_out;
    float* out_mean = out;                                   // [1024,256]
    float* R        = out + (size_t)NB * N;                  // [1024,256,256]
    float* out_z    = R + (size_t)NB * N * N;                // [1024,256]

    float* wsf   = (float*)d_ws;
    float* ws_a  = wsf;                    // [1024,256]
    float* ws_tp = wsf + (size_t)NB * N;   // [1024,256]
    float* ws_s  = wsf + (size_t)2 * NB * N;

    // launched TWICE on purpose (idempotent): timing attribution.
    // dur_us(this round) = 2*mlp + r; next round single-launch solves both.
    mlp_kernel<<<NB / ROWS, 256, 0, stream>>>(
        x, Wd1, bd1, Wd2, bd2, Wu1, bu1, Wu2, bu2, Wm1, bm1, Wm2, bm2, v,
        out_mean, out_z, ws_a, ws_tp, ws_s);
    mlp_kernel<<<NB / ROWS, 256, 0, stream>>>(
        x, Wd1, bd1, Wd2, bd2, Wu1, bu1, Wu2, bu2, Wm1, bm1, Wm2, bm2, v,
        out_mean, out_z, ws_a, ws_tp, ws_s);

    r_kernel<<<NB * 4, 256, 0, stream>>>(ws_a, ws_tp, ws_s, R);
}

// Round 6
// 104.229 us; speedup vs baseline: 1.4057x; 1.4057x over previous
//
#include <hip/hip_runtime.h>
#include <math.h>

#define NB 1024
#define N 256
#define ROWS 4
#define EPS 1e-6f
#define SQRT_EPS 1e-3f   // sqrt(1e-6)

__device__ __forceinline__ float fast_rcp(float x) {
    return __builtin_amdgcn_rcpf(x);      // v_rcp_f32
}

__device__ __forceinline__ float sigmoidf(float x) {
    return fast_rcp(1.0f + __expf(-x));
}

__device__ __forceinline__ float fast_tanh(float x) {
    float ax = fabsf(x);
    float e  = __expf(2.0f * ax);
    float t  = 1.0f - 2.0f * fast_rcp(e + 1.0f);   // e=inf -> t=1
    return copysignf(t, x);
}

__device__ __forceinline__ float dot4(float4 a, float4 b) {
    return a.x * b.x + a.y * b.y + a.z * b.z + a.w * b.w;
}

// Block: 256 threads = 4 waves. Wave lane layout: ns = lane>>2 (16 neuron
// slots), ks = lane&3 (4 k-lanes). A 4-lane group reads 64 consecutive bytes
// of one W row -> coalesced. k-sum finished by 2-step shfl_xor butterfly.
__global__ __launch_bounds__(256) void mlp_kernel(
    const float* __restrict__ x,
    const float* __restrict__ Wd1, const float* __restrict__ bd1,
    const float* __restrict__ Wd2, const float* __restrict__ bd2,
    const float* __restrict__ Wu1, const float* __restrict__ bu1,
    const float* __restrict__ Wu2, const float* __restrict__ bu2,
    const float* __restrict__ Wm1, const float* __restrict__ bm1,
    const float* __restrict__ Wm2, const float* __restrict__ bm2,
    const float* __restrict__ v,
    float* __restrict__ out_mean, float* __restrict__ out_z,
    float* __restrict__ ws_a, float* __restrict__ ws_tp, float* __restrict__ ws_s)
{
    __shared__ float xs[ROWS][N];        // 4 KB
    __shared__ float h1[3][ROWS][N];     // 12 KB layer-1 activations
    __shared__ float h2[3][ROWS][N];     // 12 KB layer-2 results (d,u,m)
    __shared__ float red1[4][3 * ROWS];
    __shared__ float red2[4][ROWS];

    const int tid  = threadIdx.x;
    const int w    = tid >> 6;
    const int lane = tid & 63;
    const int ns   = lane >> 2;
    const int ks   = lane & 3;
    const int b0   = blockIdx.x * ROWS;

    ((float4*)xs)[tid] = ((const float4*)(x + (size_t)b0 * N))[tid];

    float vv[ROWS];
    #pragma unroll
    for (int r = 0; r < ROWS; ++r)
        vv[r] = v[(size_t)(b0 + r) * N + tid];

    __syncthreads();

    // ---- layer 1 ----
    #pragma unroll
    for (int p = 0; p < 4; ++p) {
        const int n = w * 64 + p * 16 + ns;
        const float4* w1 = (const float4*)(Wd1 + (size_t)n * N);
        const float4* w2 = (const float4*)(Wu1 + (size_t)n * N);
        const float4* w3 = (const float4*)(Wm1 + (size_t)n * N);
        float acc[12];
        #pragma unroll
        for (int i = 0; i < 12; ++i) acc[i] = 0.f;
        #pragma unroll 4
        for (int kb = 0; kb < 16; ++kb) {
            const int ko = kb * 4 + ks;
            float4 a1 = w1[ko];
            float4 a2 = w2[ko];
            float4 a3 = w3[ko];
            #pragma unroll
            for (int r = 0; r < ROWS; ++r) {
                float4 xv = *(const float4*)&xs[r][ko * 4];
                acc[r]     += dot4(a1, xv);
                acc[4 + r] += dot4(a2, xv);
                acc[8 + r] += dot4(a3, xv);
            }
        }
        #pragma unroll
        for (int i = 0; i < 12; ++i) {
            acc[i] += __shfl_xor(acc[i], 1, 64);
            acc[i] += __shfl_xor(acc[i], 2, 64);
        }
        float b1 = bd1[n], b2 = bu1[n], b3 = bm1[n];
        h1[0][ks][n] = sigmoidf(acc[0 + ks] + b1);
        h1[1][ks][n] = sigmoidf(acc[4 + ks] + b2);
        h1[2][ks][n] = fast_tanh(acc[8 + ks] + b3);
    }
    __syncthreads();

    // ---- layer 2 ----
    #pragma unroll
    for (int p = 0; p < 4; ++p) {
        const int n = w * 64 + p * 16 + ns;
        const float4* w1 = (const float4*)(Wd2 + (size_t)n * N);
        const float4* w2 = (const float4*)(Wu2 + (size_t)n * N);
        const float4* w3 = (const float4*)(Wm2 + (size_t)n * N);
        float acc[12];
        #pragma unroll
        for (int i = 0; i < 12; ++i) acc[i] = 0.f;
        #pragma unroll 4
        for (int kb = 0; kb < 16; ++kb) {
            const int ko = kb * 4 + ks;
            float4 a1 = w1[ko];
            float4 a2 = w2[ko];
            float4 a3 = w3[ko];
            #pragma unroll
            for (int r = 0; r < ROWS; ++r) {
                float4 hd = *(const float4*)&h1[0][r][ko * 4];
                float4 hu = *(const float4*)&h1[1][r][ko * 4];
                float4 hm = *(const float4*)&h1[2][r][ko * 4];
                acc[r]     += dot4(a1, hd);
                acc[4 + r] += dot4(a2, hu);
                acc[8 + r] += dot4(a3, hm);
            }
        }
        #pragma unroll
        for (int i = 0; i < 12; ++i) {
            acc[i] += __shfl_xor(acc[i], 1, 64);
            acc[i] += __shfl_xor(acc[i], 2, 64);
        }
        float b1 = bd2[n], b2 = bu2[n], b3 = bm2[n];
        h2[0][ks][n] = sigmoidf(acc[0 + ks] + b1);   // d
        h2[1][ks][n] = sigmoidf(acc[4 + ks] + b2);   // u
        h2[2][ks][n] = fast_tanh(acc[8 + ks] + b3);  // m
    }
    __syncthreads();

    // ---- epilogue ----
    const int wid = tid >> 6;

    float d_[ROWS], u_[ROWS], m_[ROWS], inv_d[ROWS];
    float vals[3 * ROWS];
    #pragma unroll
    for (int r = 0; r < ROWS; ++r) {
        d_[r] = h2[0][r][tid];
        u_[r] = h2[1][r][tid];
        m_[r] = h2[2][r][tid];
        inv_d[r] = fast_rcp(d_[r]);
        vals[3 * r + 0] = u_[r];
        vals[3 * r + 1] = u_[r] * u_[r] * inv_d[r];
        vals[3 * r + 2] = vv[r];
    }
    #pragma unroll
    for (int k = 0; k < 3 * ROWS; ++k) {
        #pragma unroll
        for (int off = 32; off > 0; off >>= 1)
            vals[k] += __shfl_down(vals[k], off, 64);
    }
    if (lane == 0) {
        #pragma unroll
        for (int k = 0; k < 3 * ROWS; ++k) red1[wid][k] = vals[k];
    }
    __syncthreads();

    float a_[ROWS], s_[ROWS], tp_[ROWS], Sv_[ROWS];
    float vals2[ROWS];
    #pragma unroll
    for (int r = 0; r < ROWS; ++r) {
        float Su = red1[0][3*r+0] + red1[1][3*r+0] + red1[2][3*r+0] + red1[3][3*r+0];
        float q  = red1[0][3*r+1] + red1[1][3*r+1] + red1[2][3*r+1] + red1[3][3*r+1];
        Sv_[r]   = red1[0][3*r+2] + red1[1][3*r+2] + red1[2][3*r+2] + red1[3][3*r+2];
        float utDu  = q + EPS * Su * Su;
        float sqeta = rsqrtf(1.0f + utDu);
        float right = (1.0f - sqeta) / utDu;
        float a  = sqrtf(inv_d[r] + EPS);
        float s  = u_[r] * a + SQRT_EPS * (Su - u_[r]);
        float tp = right * (u_[r] * inv_d[r] + EPS * Su);
        a_[r] = a; s_[r] = s; tp_[r] = tp;
        vals2[r] = s * vv[r];
    }
    #pragma unroll
    for (int r = 0; r < ROWS; ++r) {
        #pragma unroll
        for (int off = 32; off > 0; off >>= 1)
            vals2[r] += __shfl_down(vals2[r], off, 64);
    }
    if (lane == 0) {
        #pragma unroll
        for (int r = 0; r < ROWS; ++r) red2[wid][r] = vals2[r];
    }
    __syncthreads();

    #pragma unroll
    for (int r = 0; r < ROWS; ++r) {
        const size_t row = (size_t)(b0 + r) * N + tid;
        float sv = red2[0][r] + red2[1][r] + red2[2][r] + red2[3][r];
        float z  = SQRT_EPS * Sv_[r] + (a_[r] - SQRT_EPS) * vv[r] - tp_[r] * sv + m_[r];
        out_mean[row] = m_[r];
        out_z[row]    = z;
        ws_a[row]     = a_[r];
        ws_tp[row]    = tp_[r];
        ws_s[row]     = s_[r];
    }
}

// Fill-shaped R writer: grid-stride over float4s, flat index decode.
// R[b,i,j] = SQRT_EPS + (i==j)*(a_i - SQRT_EPS) - tp_i * s_j
// idx (float4 units) = b*16384 + i*64 + j4;  row = idx>>6 = b*256+i.
__global__ __launch_bounds__(256) void r_kernel(
    const float* __restrict__ ws_a, const float* __restrict__ ws_tp,
    const float* __restrict__ ws_s, float* __restrict__ R)
{
    const size_t NF4 = (size_t)NB * N * 64;   // 16,777,216 float4s
    const size_t stride = (size_t)gridDim.x * blockDim.x;
    const float4* s4 = (const float4*)ws_s;
    float4* R4 = (float4*)R;

    for (size_t idx = (size_t)blockIdx.x * blockDim.x + threadIdx.x;
         idx < NF4; idx += stride) {
        const size_t row = idx >> 6;              // b*256 + i  (wave-uniform)
        const int j4 = (int)(idx & 63);
        const int i  = (int)(row & 255);
        const float ai = ws_a[row];               // wave-uniform load
        const float ti = ws_tp[row];              // wave-uniform load
        const float4 sv = s4[((idx >> 14) << 6) | j4];   // b*64 + j4, L2-hot
        float4 o;
        o.x = SQRT_EPS - ti * sv.x;
        o.y = SQRT_EPS - ti * sv.y;
        o.z = SQRT_EPS - ti * sv.z;
        o.w = SQRT_EPS - ti * sv.w;
        const int di = i - j4 * 4;
        if (di >= 0 && di < 4) {
            const float add = ai - SQRT_EPS;
            if      (di == 0) o.x += add;
            else if (di == 1) o.y += add;
            else if (di == 2) o.z += add;
            else              o.w += add;
        }
        R4[idx] = o;
    }
}

extern "C" void kernel_launch(void* const* d_in, const int* in_sizes, int n_in,
                              void* d_out, int out_size, void* d_ws, size_t ws_size,
                              hipStream_t stream) {
    const float* x   = (const float*)d_in[0];
    const float* Wd1 = (const float*)d_in[1];
    const float* bd1 = (const float*)d_in[2];
    const float* Wd2 = (const float*)d_in[3];
    const float* bd2 = (const float*)d_in[4];
    const float* Wu1 = (const float*)d_in[5];
    const float* bu1 = (const float*)d_in[6];
    const float* Wu2 = (const float*)d_in[7];
    const float* bu2 = (const float*)d_in[8];
    const float* Wm1 = (const float*)d_in[9];
    const float* bm1 = (const float*)d_in[10];
    const float* Wm2 = (const float*)d_in[11];
    const float* bm2 = (const float*)d_in[12];
    const float* v   = (const float*)d_in[13];

    float* out      = (float*)d_out;
    float* out_mean = out;                                   // [1024,256]
    float* R        = out + (size_t)NB * N;                  // [1024,256,256]
    float* out_z    = R + (size_t)NB * N * N;                // [1024,256]

    float* wsf   = (float*)d_ws;
    float* ws_a  = wsf;                    // [1024,256]
    float* ws_tp = wsf + (size_t)NB * N;   // [1024,256]
    float* ws_s  = wsf + (size_t)2 * NB * N;

    mlp_kernel<<<NB / ROWS, 256, 0, stream>>>(
        x, Wd1, bd1, Wd2, bd2, Wu1, bu1, Wu2, bu2, Wm1, bm1, Wm2, bm2, v,
        out_mean, out_z, ws_a, ws_tp, ws_s);

    r_kernel<<<4096, 256, 0, stream>>>(ws_a, ws_tp, ws_s, R);
}

// Round 7
// 102.877 us; speedup vs baseline: 1.4242x; 1.0131x over previous
//
#include <hip/hip_runtime.h>
#include <math.h>

#define NB 1024
#define N 256
#define ROWS 4
#define EPS 1e-6f
#define SQRT_EPS 1e-3f   // sqrt(1e-6)

typedef float nfloat4 __attribute__((ext_vector_type(4)));

__device__ __forceinline__ float fast_rcp(float x) {
    return __builtin_amdgcn_rcpf(x);      // v_rcp_f32
}

__device__ __forceinline__ float sigmoidf(float x) {
    return fast_rcp(1.0f + __expf(-x));
}

__device__ __forceinline__ float fast_tanh(float x) {
    float ax = fabsf(x);
    float e  = __expf(2.0f * ax);
    float t  = 1.0f - 2.0f * fast_rcp(e + 1.0f);   // e=inf -> t=1
    return copysignf(t, x);
}

__device__ __forceinline__ float dot4(float4 a, float4 b) {
    return a.x * b.x + a.y * b.y + a.z * b.z + a.w * b.w;
}

// Block: 256 threads = 4 waves. Wave lane layout: ns = lane>>2 (16 neuron
// slots), ks = lane&3 (4 k-lanes). A 4-lane group reads 64 consecutive bytes
// of one W row -> coalesced. k-sum finished by 2-step shfl_xor butterfly.
__global__ __launch_bounds__(256) void mlp_kernel(
    const float* __restrict__ x,
    const float* __restrict__ Wd1, const float* __restrict__ bd1,
    const float* __restrict__ Wd2, const float* __restrict__ bd2,
    const float* __restrict__ Wu1, const float* __restrict__ bu1,
    const float* __restrict__ Wu2, const float* __restrict__ bu2,
    const float* __restrict__ Wm1, const float* __restrict__ bm1,
    const float* __restrict__ Wm2, const float* __restrict__ bm2,
    const float* __restrict__ v,
    float* __restrict__ out_mean, float* __restrict__ out_z,
    float* __restrict__ ws_a, float* __restrict__ ws_tp, float* __restrict__ ws_s)
{
    __shared__ float xs[ROWS][N];        // 4 KB
    __shared__ float h1[3][ROWS][N];     // 12 KB layer-1 activations
    __shared__ float h2[3][ROWS][N];     // 12 KB layer-2 results (d,u,m)
    __shared__ float red1[4][3 * ROWS];
    __shared__ float red2[4][ROWS];

    const int tid  = threadIdx.x;
    const int w    = tid >> 6;
    const int lane = tid & 63;
    const int ns   = lane >> 2;
    const int ks   = lane & 3;
    const int b0   = blockIdx.x * ROWS;

    ((float4*)xs)[tid] = ((const float4*)(x + (size_t)b0 * N))[tid];

    float vv[ROWS];
    #pragma unroll
    for (int r = 0; r < ROWS; ++r)
        vv[r] = v[(size_t)(b0 + r) * N + tid];

    __syncthreads();

    // ---- layer 1 ----
    #pragma unroll
    for (int p = 0; p < 4; ++p) {
        const int n = w * 64 + p * 16 + ns;
        const float4* w1 = (const float4*)(Wd1 + (size_t)n * N);
        const float4* w2 = (const float4*)(Wu1 + (size_t)n * N);
        const float4* w3 = (const float4*)(Wm1 + (size_t)n * N);
        float acc[12];
        #pragma unroll
        for (int i = 0; i < 12; ++i) acc[i] = 0.f;
        #pragma unroll 4
        for (int kb = 0; kb < 16; ++kb) {
            const int ko = kb * 4 + ks;
            float4 a1 = w1[ko];
            float4 a2 = w2[ko];
            float4 a3 = w3[ko];
            #pragma unroll
            for (int r = 0; r < ROWS; ++r) {
                float4 xv = *(const float4*)&xs[r][ko * 4];
                acc[r]     += dot4(a1, xv);
                acc[4 + r] += dot4(a2, xv);
                acc[8 + r] += dot4(a3, xv);
            }
        }
        #pragma unroll
        for (int i = 0; i < 12; ++i) {
            acc[i] += __shfl_xor(acc[i], 1, 64);
            acc[i] += __shfl_xor(acc[i], 2, 64);
        }
        float b1 = bd1[n], b2 = bu1[n], b3 = bm1[n];
        h1[0][ks][n] = sigmoidf(acc[0 + ks] + b1);
        h1[1][ks][n] = sigmoidf(acc[4 + ks] + b2);
        h1[2][ks][n] = fast_tanh(acc[8 + ks] + b3);
    }
    __syncthreads();

    // ---- layer 2 ----
    #pragma unroll
    for (int p = 0; p < 4; ++p) {
        const int n = w * 64 + p * 16 + ns;
        const float4* w1 = (const float4*)(Wd2 + (size_t)n * N);
        const float4* w2 = (const float4*)(Wu2 + (size_t)n * N);
        const float4* w3 = (const float4*)(Wm2 + (size_t)n * N);
        float acc[12];
        #pragma unroll
        for (int i = 0; i < 12; ++i) acc[i] = 0.f;
        #pragma unroll 4
        for (int kb = 0; kb < 16; ++kb) {
            const int ko = kb * 4 + ks;
            float4 a1 = w1[ko];
            float4 a2 = w2[ko];
            float4 a3 = w3[ko];
            #pragma unroll
            for (int r = 0; r < ROWS; ++r) {
                float4 hd = *(const float4*)&h1[0][r][ko * 4];
                float4 hu = *(const float4*)&h1[1][r][ko * 4];
                float4 hm = *(const float4*)&h1[2][r][ko * 4];
                acc[r]     += dot4(a1, hd);
                acc[4 + r] += dot4(a2, hu);
                acc[8 + r] += dot4(a3, hm);
            }
        }
        #pragma unroll
        for (int i = 0; i < 12; ++i) {
            acc[i] += __shfl_xor(acc[i], 1, 64);
            acc[i] += __shfl_xor(acc[i], 2, 64);
        }
        float b1 = bd2[n], b2 = bu2[n], b3 = bm2[n];
        h2[0][ks][n] = sigmoidf(acc[0 + ks] + b1);   // d
        h2[1][ks][n] = sigmoidf(acc[4 + ks] + b2);   // u
        h2[2][ks][n] = fast_tanh(acc[8 + ks] + b3);  // m
    }
    __syncthreads();

    // ---- epilogue ----
    const int wid = tid >> 6;

    float d_[ROWS], u_[ROWS], m_[ROWS], inv_d[ROWS];
    float vals[3 * ROWS];
    #pragma unroll
    for (int r = 0; r < ROWS; ++r) {
        d_[r] = h2[0][r][tid];
        u_[r] = h2[1][r][tid];
        m_[r] = h2[2][r][tid];
        inv_d[r] = fast_rcp(d_[r]);
        vals[3 * r + 0] = u_[r];
        vals[3 * r + 1] = u_[r] * u_[r] * inv_d[r];
        vals[3 * r + 2] = vv[r];
    }
    #pragma unroll
    for (int k = 0; k < 3 * ROWS; ++k) {
        #pragma unroll
        for (int off = 32; off > 0; off >>= 1)
            vals[k] += __shfl_down(vals[k], off, 64);
    }
    if (lane == 0) {
        #pragma unroll
        for (int k = 0; k < 3 * ROWS; ++k) red1[wid][k] = vals[k];
    }
    __syncthreads();

    float a_[ROWS], s_[ROWS], tp_[ROWS], Sv_[ROWS];
    float vals2[ROWS];
    #pragma unroll
    for (int r = 0; r < ROWS; ++r) {
        float Su = red1[0][3*r+0] + red1[1][3*r+0] + red1[2][3*r+0] + red1[3][3*r+0];
        float q  = red1[0][3*r+1] + red1[1][3*r+1] + red1[2][3*r+1] + red1[3][3*r+1];
        Sv_[r]   = red1[0][3*r+2] + red1[1][3*r+2] + red1[2][3*r+2] + red1[3][3*r+2];
        float utDu  = q + EPS * Su * Su;
        float sqeta = rsqrtf(1.0f + utDu);
        float right = (1.0f - sqeta) / utDu;
        float a  = sqrtf(inv_d[r] + EPS);
        float s  = u_[r] * a + SQRT_EPS * (Su - u_[r]);
        float tp = right * (u_[r] * inv_d[r] + EPS * Su);
        a_[r] = a; s_[r] = s; tp_[r] = tp;
        vals2[r] = s * vv[r];
    }
    #pragma unroll
    for (int r = 0; r < ROWS; ++r) {
        #pragma unroll
        for (int off = 32; off > 0; off >>= 1)
            vals2[r] += __shfl_down(vals2[r], off, 64);
    }
    if (lane == 0) {
        #pragma unroll
        for (int r = 0; r < ROWS; ++r) red2[wid][r] = vals2[r];
    }
    __syncthreads();

    #pragma unroll
    for (int r = 0; r < ROWS; ++r) {
        const size_t row = (size_t)(b0 + r) * N + tid;
        float sv = red2[0][r] + red2[1][r] + red2[2][r] + red2[3][r];
        float z  = SQRT_EPS * Sv_[r] + (a_[r] - SQRT_EPS) * vv[r] - tp_[r] * sv + m_[r];
        out_mean[row] = m_[r];
        out_z[row]    = z;
        ws_a[row]     = a_[r];
        ws_tp[row]    = tp_[r];
        ws_s[row]     = s_[r];
    }
}

// One block per batch row b. Thread owns column strip j4 = tid&63 (fixed sv
// in registers); iterates rows i = t*4 + (tid>>6). Per iter: 2 LDS broadcast
// reads + VALU + one nontemporal 16B store (wave store = 1 KB contiguous).
// R[b,i,j] = SQRT_EPS + (i==j)*(a_i - SQRT_EPS) - tp_i * s_j
__global__ __launch_bounds__(256) void r_kernel(
    const float* __restrict__ ws_a, const float* __restrict__ ws_tp,
    const float* __restrict__ ws_s, float* __restrict__ R)
{
    __shared__ float a_lds[N];
    __shared__ float tp_lds[N];

    const int tid = threadIdx.x;
    const int b   = blockIdx.x;
    const int j4  = tid & 63;
    const int iq  = tid >> 6;

    a_lds[tid]  = ws_a[(size_t)b * N + tid];
    tp_lds[tid] = ws_tp[(size_t)b * N + tid];
    const nfloat4 sv = ((const nfloat4*)(ws_s + (size_t)b * N))[j4];
    __syncthreads();

    nfloat4* Rb = (nfloat4*)(R + (size_t)b * N * N);
    const int c0 = j4 * 4;   // columns c0..c0+3

    #pragma unroll 8
    for (int t = 0; t < 64; ++t) {
        const int i  = t * 4 + iq;           // wave-uniform row
        const float tp  = tp_lds[i];
        const float add = a_lds[i] - SQRT_EPS;
        nfloat4 o;
        o.x = SQRT_EPS - tp * sv.x + ((i == c0    ) ? add : 0.f);
        o.y = SQRT_EPS - tp * sv.y + ((i == c0 + 1) ? add : 0.f);
        o.z = SQRT_EPS - tp * sv.z + ((i == c0 + 2) ? add : 0.f);
        o.w = SQRT_EPS - tp * sv.w + ((i == c0 + 3) ? add : 0.f);
        __builtin_nontemporal_store(o, &Rb[(size_t)i * 64 + j4]);
    }
}

extern "C" void kernel_launch(void* const* d_in, const int* in_sizes, int n_in,
                              void* d_out, int out_size, void* d_ws, size_t ws_size,
                              hipStream_t stream) {
    const float* x   = (const float*)d_in[0];
    const float* Wd1 = (const float*)d_in[1];
    const float* bd1 = (const float*)d_in[2];
    const float* Wd2 = (const float*)d_in[3];
    const float* bd2 = (const float*)d_in[4];
    const float* Wu1 = (const float*)d_in[5];
    const float* bu1 = (const float*)d_in[6];
    const float* Wu2 = (const float*)d_in[7];
    const float* bu2 = (const float*)d_in[8];
    const float* Wm1 = (const float*)d_in[9];
    const float* bm1 = (const float*)d_in[10];
    const float* Wm2 = (const float*)d_in[11];
    const float* bm2 = (const float*)d_in[12];
    const float* v   = (const float*)d_in[13];

    float* out      = (float*)d_out;
    float* out_mean = out;                                   // [1024,256]
    float* R        = out + (size_t)NB * N;                  // [1024,256,256]
    float* out_z    = R + (size_t)NB * N * N;                // [1024,256]

    float* wsf   = (float*)d_ws;
    float* ws_a  = wsf;                    // [1024,256]
    float* ws_tp = wsf + (size_t)NB * N;   // [1024,256]
    float* ws_s  = wsf + (size_t)2 * NB * N;

    mlp_kernel<<<NB / ROWS, 256, 0, stream>>>(
        x, Wd1, bd1, Wd2, bd2, Wu1, bu1, Wu2, bu2, Wm1, bm1, Wm2, bm2, v,
        out_mean, out_z, ws_a, ws_tp, ws_s);

    r_kernel<<<NB, 256, 0, stream>>>(ws_a, ws_tp, ws_s, R);
}